// Round 1
// baseline (5436.545 us; speedup 1.0000x reference)
//
#include <hip/hip_runtime.h>

// psRNN round 8: single-XCD replicas, 1 step/round, sc0-only critical path.
// r7 counters (MfmaUtil 16%, VALUBusy 16%, HBM 3%, 4.23us per 2-step round =
// ~10k cycles, of which only ~1.9k is MFMA) => bound by the cross-XCD sync
// chain (sc1 dual-publish drain + LLC flag RTT + 16MB/round LLC broadcast),
// not by any pipe. The W^2 2-step trick existed only to amortize that sync.
// Restructure: batch split 8 ways (8 reps x batch 8); each rep lives on ONE
// XCD (32 blocks x 1/CU, 64 state rows each; W-only frags = 64x2048x2B =
// 256KB/CU of registers -- W^2 would need 2 XCDs, which is exactly why r7 was
// cross-XCD). All state exchange through the XCD's own L2 via sc0 stores /
// vmcnt(0) / sc0 loads (r2/r5-proven same-XCD path). Flags polled sc0 with an
// agent-scope fallback every 64 spins (deadlock-proof if sc0 polling were
// ever L1-stale). c = A*cos(omega*s+u) computed per-owner in f32 AFTER the
// publish (off the serial chain) and never broadcast. 512 rounds x ~1.1us
// predicted. conv/W^2 kernels deleted.

typedef _Float16 half_t;
typedef _Float16 half8 __attribute__((ext_vector_type(8)));
typedef float f32x4 __attribute__((ext_vector_type(4)));

#define NHID 2048
#define NOUT 64
#define N_ROUNDS 512
#define ST_UNIT 16384   // halfs per (buf,rep): [8 batch][2048 n]

#define MFMA16(A, B, C) __builtin_amdgcn_mfma_f32_16x16x32_f16(A, B, C, 0, 0, 0)

// ws layout (bytes):
//   [0, 4096)        : flagsL uint[8][128]  (sc0 / XCD-L2 copy, monotonic)
//   [8192, 12288)    : flagsG uint[8][128]  (agent / LLC fallback copy)
//   [16384, 16416)   : roster uint[8]       (per-XCD block counter)
//   [1M, 1M+768K)    : St  half[3][8][ST_UNIT]   (rotating state bufs, sc0)
//   [2M, 2M+256K)    : StFinal half[8][ST_UNIT]  (final state, sc1/LLC)

__device__ __forceinline__ half8 cvt8(float4 lo, float4 hi) {
  half8 h;
  h[0] = (half_t)lo.x; h[1] = (half_t)lo.y; h[2] = (half_t)lo.z; h[3] = (half_t)lo.w;
  h[4] = (half_t)hi.x; h[5] = (half_t)hi.y; h[6] = (half_t)hi.z; h[7] = (half_t)hi.w;
  return h;
}

__global__ void psrnn_init_kernel(unsigned* flagsL, unsigned* flagsG,
                                  unsigned* roster, uint4* st) {
  int g = blockIdx.x * blockDim.x + threadIdx.x;  // 16384 threads
  uint4 v; v.x = 0x3C003C00u; v.y = 0x3C003C00u; v.z = 0x3C003C00u; v.w = 0x3C003C00u;
  st[g] = v;  // buf0, all 8 reps := fp16 1.0 (16384 uint4 = 8*32KB)
  if (g < 1024) { flagsL[g] = 1u; flagsG[g] = 1u; }
  else if (g < 1032) roster[g - 1024] = 0u;
}

__global__ __launch_bounds__(256, 1) void psrnn_main_kernel(
    const float* __restrict__ x,      // [512][64][64]
    const float* __restrict__ Wi_w,   // [2048][64]
    const float* __restrict__ Wi_b,   // [2048]
    const float* __restrict__ Wh_w,   // [2048][2048]
    const float* __restrict__ Av,     // [2048]
    const float* __restrict__ Om,     // [2048]
    unsigned* __restrict__ flagsL,
    unsigned* __restrict__ flagsG,
    unsigned* __restrict__ roster,
    half_t* __restrict__ St,          // rotating bufs (XCD-local, sc0)
    half_t* __restrict__ StFinal)     // final state (LLC, sc1)
{
  extern __shared__ char lds_force[];        // +60KB dyn: forces 1 block/CU
  __shared__ float ybuf[2][4][4][16][9];     // [par][wave][nt][row16][batch8+pad]
  __shared__ float ubuf[2][4][16][9];        // [par][nt][row16][batch8+pad]
  __shared__ unsigned slot_sh;
  (void)lds_force;

  const int tid = threadIdx.x, w = tid >> 6, lane = tid & 63;
  const int lm = lane & 15, kg = lane >> 4, lb = lm & 7;

  unsigned xcd;
  asm volatile("s_getreg_b32 %0, hwreg(HW_REG_XCC_ID)" : "=s"(xcd));
  const int rep = (int)(xcd & 7u);
  if (tid == 0) slot_sh = atomicAdd(&roster[rep], 1u) & 31u;
  __syncthreads();
  const int slot = (int)slot_sh;
  const int n0 = slot * 64, b0 = rep * 8;

  // ---- W B-frags: rows n0 + nt*16 + lm, K = w*512 + c*32 + kg*8 .. +8
  half8 wb[4][16];
#pragma unroll
  for (int nt = 0; nt < 4; ++nt)
#pragma unroll
    for (int c = 0; c < 16; ++c) {
      const float* p = Wh_w + (size_t)(n0 + nt * 16 + lm) * NHID + (w * 512 + c * 32 + kg * 8);
      wb[nt][c] = cvt8(*(const float4*)p, *(const float4*)(p + 4));
    }
  // Wi B-frags for u-tile nt=w: rows n0 + w*16 + lm, K = 0..64
  half8 wi0, wi1;
  {
    const float* p = Wi_w + (size_t)(n0 + w * 16 + lm) * 64 + kg * 8;
    wi0 = cvt8(*(const float4*)p, *(const float4*)(p + 4));
    wi1 = cvt8(*(const float4*)(p + 32), *(const float4*)(p + 36));
  }

  // ---- combiner constants: thread owns (batch m, local rows r0, r0+1)
  const int m = tid >> 5;            // 0..7
  const int r0 = (tid & 31) * 2;     // 0..62
  float cA2[2], cOm2[2], cB2[2];
#pragma unroll
  for (int j = 0; j < 2; ++j) {
    const int ng = n0 + r0 + j;
    cA2[j] = Av[ng]; cOm2[j] = Om[ng]; cB2[j] = Wi_b[ng];
  }
  float cpr[2];

  unsigned* const pfL  = flagsL + rep * 128 + 32 * w + (lane & 31);  // my 8 producers x 4 waves
  unsigned* const pfG  = flagsG + rep * 128 + 32 * w + (lane & 31);
  unsigned* const myfL = flagsL + rep * 128 + slot * 4 + w;
  unsigned* const myfG = flagsG + rep * 128 + slot * 4 + w;

  // ---- preloop: u_0 -> ubuf[1]; cpr = c_0 = A*cos(om*1 + u_0); prefetch x_1
  float4 xr0, xr1, xr2, xr3;
  {
    const float* xp = x + (size_t)(b0 + lb) * 64;
    xr0 = *(const float4*)(xp + kg * 8);      xr1 = *(const float4*)(xp + kg * 8 + 4);
    xr2 = *(const float4*)(xp + 32 + kg * 8); xr3 = *(const float4*)(xp + 36 + kg * 8);
    f32x4 au = {0.f, 0.f, 0.f, 0.f};
    au = MFMA16(cvt8(xr0, xr1), wi0, au);
    au = MFMA16(cvt8(xr2, xr3), wi1, au);
    if (kg < 2)
#pragma unroll
      for (int r = 0; r < 4; ++r) ubuf[1][w][lm][kg * 4 + r] = au[r];
  }
  __syncthreads();
#pragma unroll
  for (int j = 0; j < 2; ++j) {
    const int rr = r0 + j;
    const float u0 = ubuf[1][rr >> 4][rr & 15][m] + cB2[j];
    cpr[j] = cA2[j] * __cosf(cOm2[j] * 1.0f + u0);
  }
  {
    const float* xp = x + ((size_t)1 * 64 + b0 + lb) * 64;
    xr0 = *(const float4*)(xp + kg * 8);      xr1 = *(const float4*)(xp + kg * 8 + 4);
    xr2 = *(const float4*)(xp + 32 + kg * 8); xr3 = *(const float4*)(xp + 36 + kg * 8);
  }

  int bR = 0;
  for (int k = 0; k < N_ROUNDS; ++k) {
    const int bW = (bR == 2) ? 0 : bR + 1;
    const int par = k & 1;

    // ---- phase A: u_{k+1} (off the serial chain; all 4 waves, tile nt=w)
    {
      f32x4 au = {0.f, 0.f, 0.f, 0.f};
      au = MFMA16(cvt8(xr0, xr1), wi0, au);
      au = MFMA16(cvt8(xr2, xr3), wi1, au);
      if (kg < 2)
#pragma unroll
        for (int r = 0; r < 4; ++r) ubuf[par][w][lm][kg * 4 + r] = au[r];
    }

    // ---- phase B: sc0 tight-spin on my 32 producer wave-flags (same XCD L2);
    //      agent-scope fallback every 64 spins (deadlock-proof)
    {
      const unsigned tgt = (unsigned)(k + 1);
      unsigned v; int sp = 0;
      for (;;) {
        asm volatile("global_load_dword %0, %1, off sc0\n\ts_waitcnt vmcnt(0)"
                     : "=v"(v) : "v"(pfL) : "memory");
        if (__all((int)(v >= tgt))) break;
        if ((++sp & 63) == 0) {
          unsigned vg = __hip_atomic_load(pfG, __ATOMIC_RELAXED, __HIP_MEMORY_SCOPE_AGENT);
          if (__all((int)(vg >= tgt))) break;
        }
      }
    }

    // ---- phase C: s_k A-frags, K-slice [512w, +512), from XCD L2 (sc0)
    const half_t* ps = St + (size_t)(bR * 8 + rep) * ST_UNIT + lb * NHID + (w * 512 + kg * 8);
    float4 Sr[16];
    asm volatile(
        "global_load_dwordx4 %0, %16, off sc0\n\t"
        "global_load_dwordx4 %1, %16, off offset:64 sc0\n\t"
        "global_load_dwordx4 %2, %16, off offset:128 sc0\n\t"
        "global_load_dwordx4 %3, %16, off offset:192 sc0\n\t"
        "global_load_dwordx4 %4, %16, off offset:256 sc0\n\t"
        "global_load_dwordx4 %5, %16, off offset:320 sc0\n\t"
        "global_load_dwordx4 %6, %16, off offset:384 sc0\n\t"
        "global_load_dwordx4 %7, %16, off offset:448 sc0\n\t"
        "global_load_dwordx4 %8, %16, off offset:512 sc0\n\t"
        "global_load_dwordx4 %9, %16, off offset:576 sc0\n\t"
        "global_load_dwordx4 %10, %16, off offset:640 sc0\n\t"
        "global_load_dwordx4 %11, %16, off offset:704 sc0\n\t"
        "global_load_dwordx4 %12, %16, off offset:768 sc0\n\t"
        "global_load_dwordx4 %13, %16, off offset:832 sc0\n\t"
        "global_load_dwordx4 %14, %16, off offset:896 sc0\n\t"
        "global_load_dwordx4 %15, %16, off offset:960 sc0\n\t"
        "s_waitcnt vmcnt(0)"
        : "=&v"(Sr[0]), "=&v"(Sr[1]), "=&v"(Sr[2]), "=&v"(Sr[3]),
          "=&v"(Sr[4]), "=&v"(Sr[5]), "=&v"(Sr[6]), "=&v"(Sr[7]),
          "=&v"(Sr[8]), "=&v"(Sr[9]), "=&v"(Sr[10]), "=&v"(Sr[11]),
          "=&v"(Sr[12]), "=&v"(Sr[13]), "=&v"(Sr[14]), "=&v"(Sr[15])
        : "v"(ps) : "memory");

    // ---- phase D: y = W * s_k partials (64 MFMA, 4 independent acc chains)
    f32x4 a0 = {0.f,0.f,0.f,0.f}, a1 = {0.f,0.f,0.f,0.f};
    f32x4 a2 = {0.f,0.f,0.f,0.f}, a3 = {0.f,0.f,0.f,0.f};
#pragma unroll
    for (int c = 0; c < 16; ++c) {
      half8 sf = __builtin_bit_cast(half8, Sr[c]);
      a0 = MFMA16(sf, wb[0][c], a0);
      a1 = MFMA16(sf, wb[1][c], a1);
      a2 = MFMA16(sf, wb[2][c], a2);
      a3 = MFMA16(sf, wb[3][c], a3);
    }
    if (kg < 2)
#pragma unroll
      for (int r = 0; r < 4; ++r) {
        ybuf[par][w][0][lm][kg * 4 + r] = a0[r];
        ybuf[par][w][1][lm][kg * 4 + r] = a1[r];
        ybuf[par][w][2][lm][kg * 4 + r] = a2[r];
        ybuf[par][w][3][lm][kg * 4 + r] = a3[r];
      }
    __syncthreads();  // the only barrier per round

    // ---- phase E: s_{k+1} = c_k + y; publish (sc0), flag
    float s2[2];
#pragma unroll
    for (int j = 0; j < 2; ++j) {
      const int rr = r0 + j;
      const float y = ybuf[par][0][rr >> 4][rr & 15][m] + ybuf[par][1][rr >> 4][rr & 15][m] +
                      ybuf[par][2][rr >> 4][rr & 15][m] + ybuf[par][3][rr >> 4][rr & 15][m];
      s2[j] = cpr[j] + y;
    }
    {
      unsigned h0 = (unsigned)__builtin_bit_cast(unsigned short, (half_t)s2[0]);
      unsigned h1 = (unsigned)__builtin_bit_cast(unsigned short, (half_t)s2[1]);
      unsigned hv = h0 | (h1 << 16);
      const half_t* wp = St + (size_t)(bW * 8 + rep) * ST_UNIT + m * NHID + (n0 + r0);
      asm volatile("global_store_dword %0, %1, off sc0" :: "v"(wp), "v"(hv) : "memory");
      if (k == N_ROUNDS - 1) {
        const half_t* fp2 = StFinal + (size_t)rep * ST_UNIT + m * NHID + (n0 + r0);
        asm volatile("global_store_dword %0, %1, off sc1" :: "v"(fp2), "v"(hv) : "memory");
      }
    }
    asm volatile("s_waitcnt vmcnt(0)" ::: "memory");
    if (lane == 0) {
      unsigned fv = (unsigned)(k + 2);
      asm volatile("global_store_dword %0, %1, off sc0" :: "v"(myfL), "v"(fv) : "memory");
      __hip_atomic_store(myfG, fv, __ATOMIC_RELAXED, __HIP_MEMORY_SCOPE_AGENT);
    }

    // ---- phase F: c_{k+1} = A*cos(om*s_{k+1} + u_{k+1})  (off the chain)
#pragma unroll
    for (int j = 0; j < 2; ++j) {
      const int rr = r0 + j;
      const float u = ubuf[par][rr >> 4][rr & 15][m] + cB2[j];
      cpr[j] = cA2[j] * __cosf(cOm2[j] * s2[j] + u);
    }

    // ---- phase G: x prefetch for u_{k+2}
    {
      int t = k + 2;
      if (t > 511) t = 511;
      const float* xp = x + ((size_t)t * 64 + b0 + lb) * 64;
      xr0 = *(const float4*)(xp + kg * 8);      xr1 = *(const float4*)(xp + kg * 8 + 4);
      xr2 = *(const float4*)(xp + 32 + kg * 8); xr3 = *(const float4*)(xp + 36 + kg * 8);
    }
    bR = bW;
  }
}

__global__ __launch_bounds__(256) void psrnn_readout_kernel(
    const float* __restrict__ Wr_w,     // [64][2048]
    const float* __restrict__ Wr_b,     // [64]
    const half_t* __restrict__ StFinal, // [8][8][2048], LLC copy
    float* __restrict__ out)            // [64][64]
{
  const int tid = threadIdx.x, v = tid >> 6, lane = tid & 63;
  const int lm = lane & 15, kg = lane >> 4, lb = lm & 7;
  const int rep = blockIdx.x;  // 8 blocks
  const half_t* sb = StFinal + (size_t)rep * ST_UNIT;

  f32x4 acc = {0.f, 0.f, 0.f, 0.f};
  for (int cg = 0; cg < 64; ++cg) {
    half8 a = *(const half8*)(sb + (size_t)lb * NHID + cg * 32 + kg * 8);
    const float* p = Wr_w + (size_t)(v * 16 + lm) * NHID + cg * 32 + kg * 8;
    half8 b = cvt8(*(const float4*)p, *(const float4*)(p + 4));
    acc = MFMA16(a, b, acc);
  }
  if (kg < 2)
#pragma unroll
    for (int r = 0; r < 4; ++r)
      out[(rep * 8 + kg * 4 + r) * NOUT + v * 16 + lm] = acc[r] + Wr_b[v * 16 + lm];
}

extern "C" void kernel_launch(void* const* d_in, const int* in_sizes, int n_in,
                              void* d_out, int out_size, void* d_ws, size_t ws_size,
                              hipStream_t stream) {
  const float* x    = (const float*)d_in[0];
  const float* Wi_w = (const float*)d_in[1];
  const float* Wi_b = (const float*)d_in[2];
  const float* Wh_w = (const float*)d_in[3];
  const float* Av   = (const float*)d_in[4];
  const float* Om   = (const float*)d_in[5];
  const float* Wr_w = (const float*)d_in[6];
  const float* Wr_b = (const float*)d_in[7];

  unsigned* flagsL  = (unsigned*)d_ws;
  unsigned* flagsG  = (unsigned*)((char*)d_ws + 8192);
  unsigned* roster  = (unsigned*)((char*)d_ws + 16384);
  half_t*   St      = (half_t*)((char*)d_ws + (1u << 20));
  half_t*   StFinal = (half_t*)((char*)d_ws + (2u << 20));

  psrnn_init_kernel<<<64, 256, 0, stream>>>(flagsL, flagsG, roster, (uint4*)St);
  psrnn_main_kernel<<<256, 256, 61440, stream>>>(x, Wi_w, Wi_b, Wh_w, Av, Om,
                                                 flagsL, flagsG, roster, St, StFinal);
  psrnn_readout_kernel<<<8, 256, 0, stream>>>(Wr_w, Wr_b, StFinal, (float*)d_out);
}

// Round 2
// 2060.988 us; speedup vs baseline: 2.6378x; 2.6378x over previous
//
#include <hip/hip_runtime.h>

// psRNN round 9: r8 structure (single-XCD replicas, 1 step/round, sc0-only
// DATA path) + r7-PROVEN flag transport (agent-scope LLC atomics).
// r8 post-mortem: 5437us, one 45ms outlier, MfmaUtil 4% -> ~25k cy/round of
// pure waiting (~64 poll iterations). The only unproven-new element in r8 was
// the sc0 flag handshake (tight vmcnt(0) sc0 spin from 128 waves/XCD on 4 L2
// lines, agent fallback every 64 spins likely doing the real unblocking).
// Data over sc0 is r2/r5/r7-proven at 1MB/XCD/round; r8 needs only 2x that.
// This round: single-variable fix -- flags via __hip_atomic_{store,load}
// AGENT (sc0+sc1, lives at LLC, the exact transport+pressure r7 ran stably).
// Everything else byte-identical to r8.
// Predicted: ~1.5us/round -> 800-1000us total, MfmaUtil ~20%, stable.
// If still ~5ms: sc0 L2 data broadcast convicted -> revert to r7 split.

typedef _Float16 half_t;
typedef _Float16 half8 __attribute__((ext_vector_type(8)));
typedef float f32x4 __attribute__((ext_vector_type(4)));

#define NHID 2048
#define NOUT 64
#define N_ROUNDS 512
#define ST_UNIT 16384   // halfs per (buf,rep): [8 batch][2048 n]

#define MFMA16(A, B, C) __builtin_amdgcn_mfma_f32_16x16x32_f16(A, B, C, 0, 0, 0)

// ws layout (bytes):
//   [0, 4096)        : flags uint[8][128]  (agent/LLC, monotonic)
//   [16384, 16416)   : roster uint[8]      (per-XCD block counter)
//   [1M, 1M+768K)    : St  half[3][8][ST_UNIT]   (rotating state bufs, sc0)
//   [2M, 2M+256K)    : StFinal half[8][ST_UNIT]  (final state, sc1/LLC)

__device__ __forceinline__ half8 cvt8(float4 lo, float4 hi) {
  half8 h;
  h[0] = (half_t)lo.x; h[1] = (half_t)lo.y; h[2] = (half_t)lo.z; h[3] = (half_t)lo.w;
  h[4] = (half_t)hi.x; h[5] = (half_t)hi.y; h[6] = (half_t)hi.z; h[7] = (half_t)hi.w;
  return h;
}

__global__ void psrnn_init_kernel(unsigned* flags, unsigned* roster, uint4* st) {
  int g = blockIdx.x * blockDim.x + threadIdx.x;  // 16384 threads
  uint4 v; v.x = 0x3C003C00u; v.y = 0x3C003C00u; v.z = 0x3C003C00u; v.w = 0x3C003C00u;
  st[g] = v;  // buf0, all 8 reps := fp16 1.0 (16384 uint4 = 8*32KB)
  if (g < 1024) flags[g] = 1u;
  else if (g < 1032) roster[g - 1024] = 0u;
}

__global__ __launch_bounds__(256, 1) void psrnn_main_kernel(
    const float* __restrict__ x,      // [512][64][64]
    const float* __restrict__ Wi_w,   // [2048][64]
    const float* __restrict__ Wi_b,   // [2048]
    const float* __restrict__ Wh_w,   // [2048][2048]
    const float* __restrict__ Av,     // [2048]
    const float* __restrict__ Om,     // [2048]
    unsigned* __restrict__ flags,
    unsigned* __restrict__ roster,
    half_t* __restrict__ St,          // rotating bufs (XCD-local, sc0)
    half_t* __restrict__ StFinal)     // final state (LLC, sc1)
{
  extern __shared__ char lds_force[];        // +60KB dyn: forces 1 block/CU
  __shared__ float ybuf[2][4][4][16][9];     // [par][wave][nt][row16][batch8+pad]
  __shared__ float ubuf[2][4][16][9];        // [par][nt][row16][batch8+pad]
  __shared__ unsigned slot_sh;
  (void)lds_force;

  const int tid = threadIdx.x, w = tid >> 6, lane = tid & 63;
  const int lm = lane & 15, kg = lane >> 4, lb = lm & 7;

  unsigned xcd;
  asm volatile("s_getreg_b32 %0, hwreg(HW_REG_XCC_ID)" : "=s"(xcd));
  const int rep = (int)(xcd & 7u);
  if (tid == 0) slot_sh = atomicAdd(&roster[rep], 1u) & 31u;
  __syncthreads();
  const int slot = (int)slot_sh;
  const int n0 = slot * 64, b0 = rep * 8;

  // ---- W B-frags: rows n0 + nt*16 + lm, K = w*512 + c*32 + kg*8 .. +8
  half8 wb[4][16];
#pragma unroll
  for (int nt = 0; nt < 4; ++nt)
#pragma unroll
    for (int c = 0; c < 16; ++c) {
      const float* p = Wh_w + (size_t)(n0 + nt * 16 + lm) * NHID + (w * 512 + c * 32 + kg * 8);
      wb[nt][c] = cvt8(*(const float4*)p, *(const float4*)(p + 4));
    }
  // Wi B-frags for u-tile nt=w: rows n0 + w*16 + lm, K = 0..64
  half8 wi0, wi1;
  {
    const float* p = Wi_w + (size_t)(n0 + w * 16 + lm) * 64 + kg * 8;
    wi0 = cvt8(*(const float4*)p, *(const float4*)(p + 4));
    wi1 = cvt8(*(const float4*)(p + 32), *(const float4*)(p + 36));
  }

  // ---- combiner constants: thread owns (batch m, local rows r0, r0+1)
  const int m = tid >> 5;            // 0..7
  const int r0 = (tid & 31) * 2;     // 0..62
  float cA2[2], cOm2[2], cB2[2];
#pragma unroll
  for (int j = 0; j < 2; ++j) {
    const int ng = n0 + r0 + j;
    cA2[j] = Av[ng]; cOm2[j] = Om[ng]; cB2[j] = Wi_b[ng];
  }
  float cpr[2];

  unsigned* const pollp = flags + rep * 128 + 32 * w + (lane & 31);  // my 8 producers x 4 waves
  unsigned* const myf   = flags + rep * 128 + slot * 4 + w;

  // ---- preloop: u_0 -> ubuf[1]; cpr = c_0 = A*cos(om*1 + u_0); prefetch x_1
  float4 xr0, xr1, xr2, xr3;
  {
    const float* xp = x + (size_t)(b0 + lb) * 64;
    xr0 = *(const float4*)(xp + kg * 8);      xr1 = *(const float4*)(xp + kg * 8 + 4);
    xr2 = *(const float4*)(xp + 32 + kg * 8); xr3 = *(const float4*)(xp + 36 + kg * 8);
    f32x4 au = {0.f, 0.f, 0.f, 0.f};
    au = MFMA16(cvt8(xr0, xr1), wi0, au);
    au = MFMA16(cvt8(xr2, xr3), wi1, au);
    if (kg < 2)
#pragma unroll
      for (int r = 0; r < 4; ++r) ubuf[1][w][lm][kg * 4 + r] = au[r];
  }
  __syncthreads();
#pragma unroll
  for (int j = 0; j < 2; ++j) {
    const int rr = r0 + j;
    const float u0 = ubuf[1][rr >> 4][rr & 15][m] + cB2[j];
    cpr[j] = cA2[j] * __cosf(cOm2[j] * 1.0f + u0);
  }
  {
    const float* xp = x + ((size_t)1 * 64 + b0 + lb) * 64;
    xr0 = *(const float4*)(xp + kg * 8);      xr1 = *(const float4*)(xp + kg * 8 + 4);
    xr2 = *(const float4*)(xp + 32 + kg * 8); xr3 = *(const float4*)(xp + 36 + kg * 8);
  }

  int bR = 0;
  for (int k = 0; k < N_ROUNDS; ++k) {
    const int bW = (bR == 2) ? 0 : bR + 1;
    const int par = k & 1;

    // ---- phase A: u_{k+1} (off the serial chain; all 4 waves, tile nt=w)
    {
      f32x4 au = {0.f, 0.f, 0.f, 0.f};
      au = MFMA16(cvt8(xr0, xr1), wi0, au);
      au = MFMA16(cvt8(xr2, xr3), wi1, au);
      if (kg < 2)
#pragma unroll
        for (int r = 0; r < 4; ++r) ubuf[par][w][lm][kg * 4 + r] = au[r];
    }

    // ---- phase B: r7-proven agent-scope (LLC) flag poll
    {
      const unsigned tgt = (unsigned)(k + 1);
      unsigned v = __hip_atomic_load(pollp, __ATOMIC_RELAXED, __HIP_MEMORY_SCOPE_AGENT);
      while (!__all((int)(v >= tgt)))
        v = __hip_atomic_load(pollp, __ATOMIC_RELAXED, __HIP_MEMORY_SCOPE_AGENT);
    }

    // ---- phase C: s_k A-frags, K-slice [512w, +512), from XCD L2 (sc0)
    const half_t* ps = St + (size_t)(bR * 8 + rep) * ST_UNIT + lb * NHID + (w * 512 + kg * 8);
    float4 Sr[16];
    asm volatile(
        "global_load_dwordx4 %0, %16, off sc0\n\t"
        "global_load_dwordx4 %1, %16, off offset:64 sc0\n\t"
        "global_load_dwordx4 %2, %16, off offset:128 sc0\n\t"
        "global_load_dwordx4 %3, %16, off offset:192 sc0\n\t"
        "global_load_dwordx4 %4, %16, off offset:256 sc0\n\t"
        "global_load_dwordx4 %5, %16, off offset:320 sc0\n\t"
        "global_load_dwordx4 %6, %16, off offset:384 sc0\n\t"
        "global_load_dwordx4 %7, %16, off offset:448 sc0\n\t"
        "global_load_dwordx4 %8, %16, off offset:512 sc0\n\t"
        "global_load_dwordx4 %9, %16, off offset:576 sc0\n\t"
        "global_load_dwordx4 %10, %16, off offset:640 sc0\n\t"
        "global_load_dwordx4 %11, %16, off offset:704 sc0\n\t"
        "global_load_dwordx4 %12, %16, off offset:768 sc0\n\t"
        "global_load_dwordx4 %13, %16, off offset:832 sc0\n\t"
        "global_load_dwordx4 %14, %16, off offset:896 sc0\n\t"
        "global_load_dwordx4 %15, %16, off offset:960 sc0\n\t"
        "s_waitcnt vmcnt(0)"
        : "=&v"(Sr[0]), "=&v"(Sr[1]), "=&v"(Sr[2]), "=&v"(Sr[3]),
          "=&v"(Sr[4]), "=&v"(Sr[5]), "=&v"(Sr[6]), "=&v"(Sr[7]),
          "=&v"(Sr[8]), "=&v"(Sr[9]), "=&v"(Sr[10]), "=&v"(Sr[11]),
          "=&v"(Sr[12]), "=&v"(Sr[13]), "=&v"(Sr[14]), "=&v"(Sr[15])
        : "v"(ps) : "memory");

    // ---- phase D: y = W * s_k partials (64 MFMA, 4 independent acc chains)
    f32x4 a0 = {0.f,0.f,0.f,0.f}, a1 = {0.f,0.f,0.f,0.f};
    f32x4 a2 = {0.f,0.f,0.f,0.f}, a3 = {0.f,0.f,0.f,0.f};
#pragma unroll
    for (int c = 0; c < 16; ++c) {
      half8 sf = __builtin_bit_cast(half8, Sr[c]);
      a0 = MFMA16(sf, wb[0][c], a0);
      a1 = MFMA16(sf, wb[1][c], a1);
      a2 = MFMA16(sf, wb[2][c], a2);
      a3 = MFMA16(sf, wb[3][c], a3);
    }
    if (kg < 2)
#pragma unroll
      for (int r = 0; r < 4; ++r) {
        ybuf[par][w][0][lm][kg * 4 + r] = a0[r];
        ybuf[par][w][1][lm][kg * 4 + r] = a1[r];
        ybuf[par][w][2][lm][kg * 4 + r] = a2[r];
        ybuf[par][w][3][lm][kg * 4 + r] = a3[r];
      }
    __syncthreads();  // the only barrier per round

    // ---- phase E: s_{k+1} = c_k + y; publish (sc0), flag (agent/LLC)
    float s2[2];
#pragma unroll
    for (int j = 0; j < 2; ++j) {
      const int rr = r0 + j;
      const float y = ybuf[par][0][rr >> 4][rr & 15][m] + ybuf[par][1][rr >> 4][rr & 15][m] +
                      ybuf[par][2][rr >> 4][rr & 15][m] + ybuf[par][3][rr >> 4][rr & 15][m];
      s2[j] = cpr[j] + y;
    }
    {
      unsigned h0 = (unsigned)__builtin_bit_cast(unsigned short, (half_t)s2[0]);
      unsigned h1 = (unsigned)__builtin_bit_cast(unsigned short, (half_t)s2[1]);
      unsigned hv = h0 | (h1 << 16);
      const half_t* wp = St + (size_t)(bW * 8 + rep) * ST_UNIT + m * NHID + (n0 + r0);
      asm volatile("global_store_dword %0, %1, off sc0" :: "v"(wp), "v"(hv) : "memory");
      if (k == N_ROUNDS - 1) {
        const half_t* fp2 = StFinal + (size_t)rep * ST_UNIT + m * NHID + (n0 + r0);
        asm volatile("global_store_dword %0, %1, off sc1" :: "v"(fp2), "v"(hv) : "memory");
      }
    }
    asm volatile("s_waitcnt vmcnt(0)" ::: "memory");
    if (lane == 0)
      __hip_atomic_store(myf, (unsigned)(k + 2), __ATOMIC_RELAXED, __HIP_MEMORY_SCOPE_AGENT);

    // ---- phase F: c_{k+1} = A*cos(om*s_{k+1} + u_{k+1})  (off the chain)
#pragma unroll
    for (int j = 0; j < 2; ++j) {
      const int rr = r0 + j;
      const float u = ubuf[par][rr >> 4][rr & 15][m] + cB2[j];
      cpr[j] = cA2[j] * __cosf(cOm2[j] * s2[j] + u);
    }

    // ---- phase G: x prefetch for u_{k+2}
    {
      int t = k + 2;
      if (t > 511) t = 511;
      const float* xp = x + ((size_t)t * 64 + b0 + lb) * 64;
      xr0 = *(const float4*)(xp + kg * 8);      xr1 = *(const float4*)(xp + kg * 8 + 4);
      xr2 = *(const float4*)(xp + 32 + kg * 8); xr3 = *(const float4*)(xp + 36 + kg * 8);
    }
    bR = bW;
  }
}

__global__ __launch_bounds__(256) void psrnn_readout_kernel(
    const float* __restrict__ Wr_w,     // [64][2048]
    const float* __restrict__ Wr_b,     // [64]
    const half_t* __restrict__ StFinal, // [8][8][2048], LLC copy
    float* __restrict__ out)            // [64][64]
{
  const int tid = threadIdx.x, v = tid >> 6, lane = tid & 63;
  const int lm = lane & 15, kg = lane >> 4, lb = lm & 7;
  const int rep = blockIdx.x;  // 8 blocks
  const half_t* sb = StFinal + (size_t)rep * ST_UNIT;

  f32x4 acc = {0.f, 0.f, 0.f, 0.f};
  for (int cg = 0; cg < 64; ++cg) {
    half8 a = *(const half8*)(sb + (size_t)lb * NHID + cg * 32 + kg * 8);
    const float* p = Wr_w + (size_t)(v * 16 + lm) * NHID + cg * 32 + kg * 8;
    half8 b = cvt8(*(const float4*)p, *(const float4*)(p + 4));
    acc = MFMA16(a, b, acc);
  }
  if (kg < 2)
#pragma unroll
    for (int r = 0; r < 4; ++r)
      out[(rep * 8 + kg * 4 + r) * NOUT + v * 16 + lm] = acc[r] + Wr_b[v * 16 + lm];
}

extern "C" void kernel_launch(void* const* d_in, const int* in_sizes, int n_in,
                              void* d_out, int out_size, void* d_ws, size_t ws_size,
                              hipStream_t stream) {
  const float* x    = (const float*)d_in[0];
  const float* Wi_w = (const float*)d_in[1];
  const float* Wi_b = (const float*)d_in[2];
  const float* Wh_w = (const float*)d_in[3];
  const float* Av   = (const float*)d_in[4];
  const float* Om   = (const float*)d_in[5];
  const float* Wr_w = (const float*)d_in[6];
  const float* Wr_b = (const float*)d_in[7];

  unsigned* flags   = (unsigned*)d_ws;
  unsigned* roster  = (unsigned*)((char*)d_ws + 16384);
  half_t*   St      = (half_t*)((char*)d_ws + (1u << 20));
  half_t*   StFinal = (half_t*)((char*)d_ws + (2u << 20));

  psrnn_init_kernel<<<64, 256, 0, stream>>>(flags, roster, (uint4*)St);
  psrnn_main_kernel<<<256, 256, 61440, stream>>>(x, Wi_w, Wi_b, Wh_w, Av, Om,
                                                 flags, roster, St, StFinal);
  psrnn_readout_kernel<<<8, 256, 0, stream>>>(Wr_w, Wr_b, StFinal, (float*)d_out);
}